// Round 4
// baseline (14435.632 us; speedup 1.0000x reference)
//
#include <hip/hip_runtime.h>
#include <math.h>

#define NFFT   1024
#define NH     512
#define HOP    64
#define NMELS  80
#define NFR    512
#define NBINS  513
#define NITER  300
#define SIGLEN 33728
#define NT     256
#define NB     256      // persistent-kernel grid (2 frames per block)

// ---- workspace layout (float offsets) ----
#define TBL_WIN  0          // win[1024]
#define TBL_TWR  1024       // twr[256]  e^{-2pi i j/512}.re
#define TBL_TWI  1280       // twi[256]  e^{-2pi i j/512}.im
#define TBL_W1R  1536       // w1r[513]
#define TBL_W1I  2056       // w1i[513]  (ends 2569)
#define BAR_SUB  2624       // 8 sub-counters, 64-float (256B) spacing -> ..3072
#define BAR_MST  3200       // master counter
#define BAR_GEN  3328       // generation word
#define OFF_MAG  4096                     // mag[512*513]
#define OFF_IWS  266752                   // iws[33728]
#define OFF_F0   300480                   // F0[512*1024]
#define OFF_F1   824768                   // F1[512*1024]

// ================= k_init (verified round-3 code, + barrier zeroing) ==========
struct __align__(16) SMemI {
    float xb[NFFT];
    float C0r[NH], C0i[NH];
    float C1r[NH], C1i[NH];
    float win[NFFT];
    float twr[256], twi[256];
    float mag[516];
};

template<int P, int SH, bool INV>
__device__ __forceinline__ void r4stage_i(const float* __restrict__ sR, const float* __restrict__ sI,
                                          float* __restrict__ dR, float* __restrict__ dI,
                                          const float* twr, const float* twi, int tid) {
    __syncthreads();
    if (tid < 128) {
        int k  = tid & (P - 1);
        int d0 = ((tid - k) << 2) + k;
        float x0r = sR[tid],       x0i = sI[tid];
        float x1r = sR[tid + 128], x1i = sI[tid + 128];
        float x2r = sR[tid + 256], x2i = sI[tid + 256];
        float x3r = sR[tid + 384], x3i = sI[tid + 384];
        int tb = k << SH;
        float c1 = twr[tb], s1 = twi[tb];
        if (INV) s1 = -s1;
        float c2 = c1 * c1 - s1 * s1, s2 = 2.f * c1 * s1;
        float c3 = c1 * c2 - s1 * s2, s3 = c1 * s2 + s1 * c2;
        float a1r = x1r * c1 - x1i * s1, a1i = x1r * s1 + x1i * c1;
        float a2r = x2r * c2 - x2i * s2, a2i = x2r * s2 + x2i * c2;
        float a3r = x3r * c3 - x3i * s3, a3i = x3r * s3 + x3i * c3;
        float t0r = x0r + a2r, t0i = x0i + a2i;
        float t1r = x0r - a2r, t1i = x0i - a2i;
        float t2r = a1r + a3r, t2i = a1i + a3i;
        float t3r = a1r - a3r, t3i = a1i - a3i;
        float i3r = INV ? -t3i : t3i;
        float i3i = INV ?  t3r : -t3r;
        dR[d0]         = t0r + t2r;  dI[d0]         = t0i + t2i;
        dR[d0 + P]     = t1r + i3r;  dI[d0 + P]     = t1i + i3i;
        dR[d0 + 2 * P] = t0r - t2r;  dI[d0 + 2 * P] = t0i - t2i;
        dR[d0 + 3 * P] = t1r - i3r;  dI[d0 + 3 * P] = t1i - i3i;
    }
}

__device__ __forceinline__ void fft_inv_i(SMemI& sm, int tid) {
    __syncthreads();
    if (tid < 128) {   // inverse stage0: C1 -> C0
        float x0r = sm.C1r[tid],       x0i = sm.C1i[tid];
        float x1r = sm.C1r[tid + 128], x1i = sm.C1i[tid + 128];
        float x2r = sm.C1r[tid + 256], x2i = sm.C1i[tid + 256];
        float x3r = sm.C1r[tid + 384], x3i = sm.C1i[tid + 384];
        float t0r = x0r + x2r, t0i = x0i + x2i;
        float t1r = x0r - x2r, t1i = x0i - x2i;
        float t2r = x1r + x3r, t2i = x1i + x3i;
        float t3r = x1r - x3r, t3i = x1i - x3i;
        float4 vr = make_float4(t0r + t2r, t1r - t3i, t0r - t2r, t1r + t3i);
        float4 vi = make_float4(t0i + t2i, t1i + t3r, t0i - t2i, t1i - t3r);
        ((float4*)sm.C0r)[tid] = vr;
        ((float4*)sm.C0i)[tid] = vi;
    }
    r4stage_i<4, 5, true>(sm.C0r, sm.C0i, sm.C1r, sm.C1i, sm.twr, sm.twi, tid);
    r4stage_i<16, 3, true>(sm.C1r, sm.C1i, sm.C0r, sm.C0i, sm.twr, sm.twi, tid);
    r4stage_i<64, 1, true>(sm.C0r, sm.C0i, sm.C1r, sm.C1i, sm.twr, sm.twi, tid);
    __syncthreads();
    {   // final radix-2: C1 -> C0
        float c = sm.twr[tid], s = -sm.twi[tid];
        float x0r = sm.C1r[tid], x0i = sm.C1i[tid];
        float x1r = sm.C1r[tid + 256], x1i = sm.C1i[tid + 256];
        float ar = x1r * c - x1i * s, ai = x1r * s + x1i * c;
        sm.C0r[tid]       = x0r + ar;  sm.C0i[tid]       = x0i + ai;
        sm.C0r[tid + 256] = x0r - ar;  sm.C0i[tid + 256] = x0i - ai;
    }
    __syncthreads();
}

extern "C" __global__ __launch_bounds__(NT)
void k_init(const float* __restrict__ mel,
            const float* __restrict__ invmel,
            float* __restrict__ ws) {
    __shared__ SMemI sm;
    const int tid = threadIdx.x;
    const int t   = blockIdx.x;

    for (int n = tid; n < NFFT; n += NT) {
        double a = (2.0 * 3.14159265358979323846) * (double)n / 1024.0;
        sm.win[n] = (float)(0.5 - 0.5 * cos(a));
    }
    for (int j = tid; j < 256; j += NT) {
        double a = (2.0 * 3.14159265358979323846) * (double)j / 512.0;
        sm.twr[j] = (float)cos(a);
        sm.twi[j] = (float)(-sin(a));
    }
    __syncthreads();
    if (t == 0) {
        for (int n = tid; n < NFFT; n += NT) ws[TBL_WIN + n] = sm.win[n];
        for (int j = tid; j < 256; j += NT) {
            ws[TBL_TWR + j] = sm.twr[j];
            ws[TBL_TWI + j] = sm.twi[j];
        }
        for (int k = tid; k < NBINS; k += NT) {
            double a = (2.0 * 3.14159265358979323846) * (double)k / 1024.0;
            ws[TBL_W1R + k] = (float)cos(a);
            ws[TBL_W1I + k] = (float)sin(a);
        }
        // zero barrier state (sub counters, master, gen)
        if (tid < 8)        ((int*)ws)[BAR_SUB + (tid << 6)] = 0;
        else if (tid == 8)  ((int*)ws)[BAR_MST] = 0;
        else if (tid == 9)  ((int*)ws)[BAR_GEN] = 0;
    }

    for (int p = t * NT + tid; p < SIGLEN; p += NFR * NT) {
        int tq = p >> 6, io = p & 63;
        float s = 0.f;
#pragma unroll
        for (int m = 0; m < 16; ++m) {
            int tp = tq - m;
            if (tp >= 0 && tp < NFR) {
                float w = sm.win[io + (m << 6)];
                s += w * w;
            }
        }
        ws[OFF_IWS + p] = (s > 1e-11f) ? (1.0f / s) : 1.0f;
    }

    if (tid < NMELS) sm.xb[tid] = exp10f(mel[tid * NFR + t]);
    __syncthreads();
    for (int k = tid; k < NBINS; k += NT) {
        const float* row = invmel + k * NMELS;
        float s = 0.f;
#pragma unroll 8
        for (int j = 0; j < NMELS; ++j) s += row[j] * sm.xb[j];
        ws[OFF_MAG + t * NBINS + k] = s;
        sm.mag[k] = s;
    }
    __syncthreads();

    for (int k = tid; k < NH; k += NT) {
        float xr = sm.mag[k], yr = sm.mag[512 - k];
        double a = (2.0 * 3.14159265358979323846) * (double)k / 1024.0;
        float c = (float)cos(a), s = (float)sin(a);
        float dr = xr - yr;
        sm.C1r[k] = ((xr + yr) - s * dr) * (1.0f / 1024.0f);
        sm.C1i[k] = (c * dr) * (1.0f / 1024.0f);
    }
    fft_inv_i(sm, tid);

    float4 w4 = ((float4*)sm.win)[tid];
    float4 o;
    o.x = w4.x * sm.C0r[2 * tid];
    o.y = w4.y * sm.C0i[2 * tid];
    o.z = w4.z * sm.C0r[2 * tid + 1];
    o.w = w4.w * sm.C0i[2 * tid + 1];
    *(float4*)&ws[OFF_F0 + (t << 10) + (tid << 2)] = o;
}

// ================= persistent Griffin-Lim kernel (2 frames / block) ==========
struct __align__(16) SM2 {
    float C0r[2][NH], C0i[2][NH];
    float C1r[2][NH], C1i[2][NH];
    float twr[256], twi[256];
};

// radix-4 stage for 2 frames: fr = tid>>7, j = tid&127
template<int P, int SH, bool INV>
__device__ __forceinline__ void r4b(const float* __restrict__ sR, const float* __restrict__ sI,
                                    float* __restrict__ dR, float* __restrict__ dI,
                                    const float* twr, const float* twi, int j) {
    int k  = j & (P - 1);
    int d0 = ((j - k) << 2) + k;
    float x0r = sR[j],       x0i = sI[j];
    float x1r = sR[j + 128], x1i = sI[j + 128];
    float x2r = sR[j + 256], x2i = sI[j + 256];
    float x3r = sR[j + 384], x3i = sI[j + 384];
    int tb = k << SH;
    float c1 = twr[tb], s1 = twi[tb];
    if (INV) s1 = -s1;
    float c2 = c1 * c1 - s1 * s1, s2 = 2.f * c1 * s1;
    float c3 = c1 * c2 - s1 * s2, s3 = c1 * s2 + s1 * c2;
    float a1r = x1r * c1 - x1i * s1, a1i = x1r * s1 + x1i * c1;
    float a2r = x2r * c2 - x2i * s2, a2i = x2r * s2 + x2i * c2;
    float a3r = x3r * c3 - x3i * s3, a3i = x3r * s3 + x3i * c3;
    float t0r = x0r + a2r, t0i = x0i + a2i;
    float t1r = x0r - a2r, t1i = x0i - a2i;
    float t2r = a1r + a3r, t2i = a1i + a3i;
    float t3r = a1r - a3r, t3i = a1i - a3i;
    float i3r = INV ? -t3i : t3i;
    float i3i = INV ?  t3r : -t3r;
    dR[d0]         = t0r + t2r;  dI[d0]         = t0i + t2i;
    dR[d0 + P]     = t1r + i3r;  dI[d0 + P]     = t1i + i3i;
    dR[d0 + 2 * P] = t0r - t2r;  dI[d0 + 2 * P] = t0i - t2i;
    dR[d0 + 3 * P] = t1r - i3r;  dI[d0 + 3 * P] = t1i - i3i;
}

extern "C" __global__ __launch_bounds__(NT)
void k_persist(float* __restrict__ ws, float* __restrict__ out) {
    __shared__ SM2 sm;
    const int tid = threadIdx.x;
    const int bid = blockIdx.x;
    const int fr  = tid >> 7;
    const int j   = tid & 127;
    const int i0  = tid << 2;
    const int j2  = 512 - tid;
    const int n0  = tid << 1;

    const float* tbl  = ws;
    const float* magg = ws + OFF_MAG;
    const float* iws  = ws + OFF_IWS;
    float* F0 = ws + OFF_F0;
    float* F1 = ws + OFF_F1;
    int*   bar = (int*)ws;

    // ---- stage twiddles to LDS (persist across all iterations) ----
    if (tid < 64)       ((float4*)sm.twr)[tid]      = ((const float4*)(tbl + TBL_TWR))[tid];
    else if (tid < 128) ((float4*)sm.twi)[tid - 64] = ((const float4*)(tbl + TBL_TWI))[tid - 64];

    // ---- per-frame constants in registers ----
    const int tA = 2 * bid, tB = tA + 1;
    float4 w4  = ((const float4*)(tbl + TBL_WIN))[tid];
    float4 iwA = *(const float4*)&iws[(tA << 6) + i0];
    float4 iwB = *(const float4*)&iws[(tB << 6) + i0];
    float mA_a, mA_b, mA_ny = 0.f, mB_a, mB_b, mB_ny = 0.f;
    float w1r_a, w1i_a, w1r_b, w1i_b;
    {
        const int sA = tA * NBINS, sB = tB * NBINS;
        if (tid == 0) {
            mA_a = magg[sA]; mA_ny = magg[sA + 512]; mA_b = magg[sA + 256];
            mB_a = magg[sB]; mB_ny = magg[sB + 512]; mB_b = magg[sB + 256];
            w1r_a = 1.f; w1i_a = 0.f; w1r_b = 0.f; w1i_b = 1.f;
        } else {
            mA_a = magg[sA + tid]; mA_b = magg[sA + j2];
            mB_a = magg[sB + tid]; mB_b = magg[sB + j2];
            w1r_a = tbl[TBL_W1R + tid]; w1i_a = tbl[TBL_W1I + tid];
            w1r_b = tbl[TBL_W1R + j2];  w1i_b = tbl[TBL_W1I + j2];
        }
    }
    const int io  = i0 & 63;
    const int tqA = tA + (i0 >> 6), tqB = tB + (i0 >> 6);

#pragma unroll 1
    for (int it = 0; it < NITER; ++it) {
        const float* Fin  = (it & 1) ? F1 : F0;
        float*       Fout = (it & 1) ? F0 : F1;

        // ---- OLA gather for both frames -> windowed packed z in C1 ----
        {
            float4 a0 = make_float4(0.f, 0.f, 0.f, 0.f);
            float4 a1 = make_float4(0.f, 0.f, 0.f, 0.f);
#pragma unroll
            for (int m = 0; m < 16; ++m) {
                int tpA = tqA - m;
                if (tpA >= 0 && tpA < NFR) {
                    float4 v = *(const float4*)&Fin[(tpA << 10) + io + (m << 6)];
                    a0.x += v.x; a0.y += v.y; a0.z += v.z; a0.w += v.w;
                }
                int tpB = tqB - m;
                if (tpB >= 0 && tpB < NFR) {
                    float4 v = *(const float4*)&Fin[(tpB << 10) + io + (m << 6)];
                    a1.x += v.x; a1.y += v.y; a1.z += v.z; a1.w += v.w;
                }
            }
            sm.C1r[0][n0]     = a0.x * iwA.x * w4.x;
            sm.C1i[0][n0]     = a0.y * iwA.y * w4.y;
            sm.C1r[0][n0 + 1] = a0.z * iwA.z * w4.z;
            sm.C1i[0][n0 + 1] = a0.w * iwA.w * w4.w;
            sm.C1r[1][n0]     = a1.x * iwB.x * w4.x;
            sm.C1i[1][n0]     = a1.y * iwB.y * w4.y;
            sm.C1r[1][n0 + 1] = a1.z * iwB.z * w4.z;
            sm.C1i[1][n0 + 1] = a1.w * iwB.w * w4.w;
        }

        // ---- forward FFT (C1 packed z -> ... -> C0 = Z) ----
        __syncthreads();
        {   // fwd stage0: C1 -> C0
            const float* zr = sm.C1r[fr];
            const float* zi = sm.C1i[fr];
            float x0r = zr[j],       x0i = zi[j];
            float x1r = zr[j + 128], x1i = zi[j + 128];
            float x2r = zr[j + 256], x2i = zi[j + 256];
            float x3r = zr[j + 384], x3i = zi[j + 384];
            float t0r = x0r + x2r, t0i = x0i + x2i;
            float t1r = x0r - x2r, t1i = x0i - x2i;
            float t2r = x1r + x3r, t2i = x1i + x3i;
            float t3r = x1r - x3r, t3i = x1i - x3i;
            float4 vr = make_float4(t0r + t2r, t1r + t3i, t0r - t2r, t1r - t3i);
            float4 vi = make_float4(t0i + t2i, t1i - t3r, t0i - t2i, t1i + t3r);
            ((float4*)sm.C0r[fr])[j] = vr;
            ((float4*)sm.C0i[fr])[j] = vi;
        }
        __syncthreads();
        r4b<4, 5, false>(sm.C0r[fr], sm.C0i[fr], sm.C1r[fr], sm.C1i[fr], sm.twr, sm.twi, j);
        __syncthreads();
        r4b<16, 3, false>(sm.C1r[fr], sm.C1i[fr], sm.C0r[fr], sm.C0i[fr], sm.twr, sm.twi, j);
        __syncthreads();
        r4b<64, 1, false>(sm.C0r[fr], sm.C0i[fr], sm.C1r[fr], sm.C1i[fr], sm.twr, sm.twi, j);
        __syncthreads();
        {   // final radix-2 fwd: C1 -> C0, both frames per thread
            float c = sm.twr[tid], s = sm.twi[tid];
#pragma unroll
            for (int f = 0; f < 2; ++f) {
                float x0r = sm.C1r[f][tid],       x0i = sm.C1i[f][tid];
                float x1r = sm.C1r[f][tid + 256], x1i = sm.C1i[f][tid + 256];
                float ar = x1r * c - x1i * s, ai = x1r * s + x1i * c;
                sm.C0r[f][tid]       = x0r + ar;  sm.C0i[f][tid]       = x0i + ai;
                sm.C0r[f][tid + 256] = x0r - ar;  sm.C0i[f][tid + 256] = x0i - ai;
            }
        }
        __syncthreads();

        // ---- fused unpack + phase projection + iFFT prep: C0 -> C1 ----
#pragma unroll
        for (int f = 0; f < 2; ++f) {
            float m_a  = f ? mB_a  : mA_a;
            float m_b  = f ? mB_b  : mA_b;
            float m_ny = f ? mB_ny : mA_ny;
            if (tid == 0) {
                float zr = sm.C0r[f][0], zi = sm.C0i[f][0];
                float e0 = zr + zi;
                float e5 = zr - zi;
                float X0 = m_a  * e0 / fmaxf(1e-8f, fabsf(e0));
                float X5 = m_ny * e5 / fmaxf(1e-8f, fabsf(e5));
                sm.C1r[f][0] = (X0 + X5) * (1.0f / 1024.0f);
                sm.C1i[f][0] = (X0 - X5) * (1.0f / 1024.0f);
                float z6r = sm.C0r[f][256], z6i = sm.C0i[f][256];
                float sc6 = m_b / fmaxf(1e-8f, sqrtf(z6r * z6r + z6i * z6i));
                float X6r = z6r * sc6, X6i = -z6i * sc6;
                sm.C1r[f][256] = X6r * (2.0f / 1024.0f);
                sm.C1i[f][256] = -X6i * (2.0f / 1024.0f);
            } else {
                float zr = sm.C0r[f][tid], zi = sm.C0i[f][tid];
                float ur = sm.C0r[f][j2],  ui = sm.C0i[f][j2];
                float er = 0.5f * (zr + ur), ei = 0.5f * (zi - ui);
                float dr = zr - ur,          di = zi + ui;
                float odr = 0.5f * di, odi = -0.5f * dr;
                float e1r = er + w1r_a * odr + w1i_a * odi;
                float e1i = ei + w1r_a * odi - w1i_a * odr;
                float e2r =  er + w1r_b * odr - w1i_b * odi;
                float e2i = -ei - w1r_b * odi - w1i_b * odr;
                float sc1 = m_a / fmaxf(1e-8f, sqrtf(e1r * e1r + e1i * e1i));
                float sc2 = m_b / fmaxf(1e-8f, sqrtf(e2r * e2r + e2i * e2i));
                float X1r = e1r * sc1, X1i = e1i * sc1;
                float X2r = e2r * sc2, X2i = e2i * sc2;
                float Er = X1r + X2r, Ei = X1i - X2i;
                float Dr = X1r - X2r, Di = X1i + X2i;
                float wdr = w1r_a * Dr - w1i_a * Di, wdi = w1r_a * Di + w1i_a * Dr;
                sm.C1r[f][tid] = (Er - wdi) * (1.0f / 1024.0f);
                sm.C1i[f][tid] = (Ei + wdr) * (1.0f / 1024.0f);
                float wdr2 = -w1r_b * Dr - w1i_b * Di, wdi2 = w1r_b * Di - w1i_b * Dr;
                sm.C1r[f][j2] = (Er - wdi2) * (1.0f / 1024.0f);
                sm.C1i[f][j2] = (-Ei + wdr2) * (1.0f / 1024.0f);
            }
        }
        __syncthreads();

        // ---- inverse FFT (C1 = A -> ... -> C0 = frame) ----
        {   // inv stage0: C1 -> C0
            const float* zr = sm.C1r[fr];
            const float* zi = sm.C1i[fr];
            float x0r = zr[j],       x0i = zi[j];
            float x1r = zr[j + 128], x1i = zi[j + 128];
            float x2r = zr[j + 256], x2i = zi[j + 256];
            float x3r = zr[j + 384], x3i = zi[j + 384];
            float t0r = x0r + x2r, t0i = x0i + x2i;
            float t1r = x0r - x2r, t1i = x0i - x2i;
            float t2r = x1r + x3r, t2i = x1i + x3i;
            float t3r = x1r - x3r, t3i = x1i - x3i;
            float4 vr = make_float4(t0r + t2r, t1r - t3i, t0r - t2r, t1r + t3i);
            float4 vi = make_float4(t0i + t2i, t1i + t3r, t0i - t2i, t1i - t3r);
            ((float4*)sm.C0r[fr])[j] = vr;
            ((float4*)sm.C0i[fr])[j] = vi;
        }
        __syncthreads();
        r4b<4, 5, true>(sm.C0r[fr], sm.C0i[fr], sm.C1r[fr], sm.C1i[fr], sm.twr, sm.twi, j);
        __syncthreads();
        r4b<16, 3, true>(sm.C1r[fr], sm.C1i[fr], sm.C0r[fr], sm.C0i[fr], sm.twr, sm.twi, j);
        __syncthreads();
        r4b<64, 1, true>(sm.C0r[fr], sm.C0i[fr], sm.C1r[fr], sm.C1i[fr], sm.twr, sm.twi, j);
        __syncthreads();
        {   // final radix-2 inv: C1 -> C0, both frames
            float c = sm.twr[tid], s = -sm.twi[tid];
#pragma unroll
            for (int f = 0; f < 2; ++f) {
                float x0r = sm.C1r[f][tid],       x0i = sm.C1i[f][tid];
                float x1r = sm.C1r[f][tid + 256], x1i = sm.C1i[f][tid + 256];
                float ar = x1r * c - x1i * s, ai = x1r * s + x1i * c;
                sm.C0r[f][tid]       = x0r + ar;  sm.C0i[f][tid]       = x0i + ai;
                sm.C0r[f][tid + 256] = x0r - ar;  sm.C0i[f][tid + 256] = x0i - ai;
            }
        }
        __syncthreads();

        // ---- store windowed frames ----
        {
            float4 o;
            o.x = w4.x * sm.C0r[0][n0];
            o.y = w4.y * sm.C0i[0][n0];
            o.z = w4.z * sm.C0r[0][n0 + 1];
            o.w = w4.w * sm.C0i[0][n0 + 1];
            *(float4*)&Fout[(tA << 10) + i0] = o;
            o.x = w4.x * sm.C0r[1][n0];
            o.y = w4.y * sm.C0i[1][n0];
            o.z = w4.z * sm.C0r[1][n0 + 1];
            o.w = w4.w * sm.C0i[1][n0 + 1];
            *(float4*)&Fout[(tB << 10) + i0] = o;
        }

        // ---- grid barrier (two-level, device scope) ----
        __threadfence();      // release this wave's stores (wbl2 across XCD L2)
        __syncthreads();
        if (tid == 0) {
            int* scnt = bar + BAR_SUB + ((bid & 7) << 6);
            int* mcnt = bar + BAR_MST;
            int* bgen = bar + BAR_GEN;
            int prev = __hip_atomic_fetch_add(scnt, 1, __ATOMIC_ACQ_REL, __HIP_MEMORY_SCOPE_AGENT);
            if (prev == (NB / 8) - 1) {
                __hip_atomic_store(scnt, 0, __ATOMIC_RELAXED, __HIP_MEMORY_SCOPE_AGENT);
                int p2 = __hip_atomic_fetch_add(mcnt, 1, __ATOMIC_ACQ_REL, __HIP_MEMORY_SCOPE_AGENT);
                if (p2 == 7) {
                    __hip_atomic_store(mcnt, 0, __ATOMIC_RELAXED, __HIP_MEMORY_SCOPE_AGENT);
                    __hip_atomic_store(bgen, it + 1, __ATOMIC_RELEASE, __HIP_MEMORY_SCOPE_AGENT);
                } else {
                    while (__hip_atomic_load(bgen, __ATOMIC_RELAXED, __HIP_MEMORY_SCOPE_AGENT) <= it)
                        __builtin_amdgcn_s_sleep(2);
                    __builtin_amdgcn_fence(__ATOMIC_ACQUIRE, "agent");
                }
            } else {
                while (__hip_atomic_load(bgen, __ATOMIC_RELAXED, __HIP_MEMORY_SCOPE_AGENT) <= it)
                    __builtin_amdgcn_s_sleep(2);
                __builtin_amdgcn_fence(__ATOMIC_ACQUIRE, "agent");
            }
        }
        __syncthreads();
    }

    // ---- epilogue: final OLA (F0 holds frames after 300 iters) -> out ----
    int p0 = (bid * NT + tid) << 2;
    if (p0 < SIGLEN) {
        int tq = p0 >> 6, ioo = p0 & 63;
        float4 acc = make_float4(0.f, 0.f, 0.f, 0.f);
#pragma unroll
        for (int m = 0; m < 16; ++m) {
            int tp = tq - m;
            if (tp >= 0 && tp < NFR) {
                float4 v = *(const float4*)&F0[(tp << 10) + ioo + (m << 6)];
                acc.x += v.x; acc.y += v.y; acc.z += v.z; acc.w += v.w;
            }
        }
        float4 iw = *(const float4*)&iws[p0];
        float4 o = make_float4(acc.x * iw.x, acc.y * iw.y, acc.z * iw.z, acc.w * iw.w);
        *(float4*)&out[p0] = o;
    }
}

extern "C" void kernel_launch(void* const* d_in, const int* in_sizes, int n_in,
                              void* d_out, int out_size, void* d_ws, size_t ws_size,
                              hipStream_t stream) {
    const float* mel    = (const float*)d_in[0];
    const float* invmel = (const float*)d_in[1];
    float* out = (float*)d_out;
    float* ws  = (float*)d_ws;

    k_init<<<NFR, NT, 0, stream>>>(mel, invmel, ws);
    k_persist<<<NB, NT, 0, stream>>>(ws, out);
}

// Round 5
// 3442.834 us; speedup vs baseline: 4.1929x; 4.1929x over previous
//
#include <hip/hip_runtime.h>
#include <math.h>

#define NFFT   1024
#define NH     512
#define HOP    64
#define NMELS  80
#define NFR    512
#define NBINS  513
#define NITER  300
#define SIGLEN 33728
#define NT     256
#define NB     512      // persistent grid: 1 frame per block, 2 blocks/CU

// ---- workspace layout (float/int offsets, 4B units) ----
#define TBL_WIN  0          // win[1024]
#define TBL_TWR  1024       // twr[256]  e^{-2pi i j/512}.re
#define TBL_TWI  1280       // twi[256]  e^{-2pi i j/512}.im
#define TBL_W1R  1536       // w1r[513]
#define TBL_W1I  2056       // w1i[513]  (ends 2569)
#define BAR_SLOT 2624       // 512 int slots  -> ..3136
#define BAR_GEN  3200       // generation word
#define OFF_MAG  4096                     // mag[512*513]
#define OFF_IWS  266752                   // iws[33728]
#define OFF_F0   300480                   // F0[512*1024]
#define OFF_F1   824768                   // F1[512*1024]

typedef unsigned long long u64;

// ---- coherent (agent-scope, L2-bypass) 16B load/store as 2x8B ----
__device__ __forceinline__ float4 coh_load4(const float* p) {
    u64 a = __hip_atomic_load((const u64*)p,       __ATOMIC_RELAXED, __HIP_MEMORY_SCOPE_AGENT);
    u64 b = __hip_atomic_load((const u64*)(p + 2), __ATOMIC_RELAXED, __HIP_MEMORY_SCOPE_AGENT);
    float2 fa, fb;
    __builtin_memcpy(&fa, &a, 8);
    __builtin_memcpy(&fb, &b, 8);
    return make_float4(fa.x, fa.y, fb.x, fb.y);
}
__device__ __forceinline__ void coh_store4(float* p, float4 v) {
    float2 fa = make_float2(v.x, v.y), fb = make_float2(v.z, v.w);
    u64 a, b;
    __builtin_memcpy(&a, &fa, 8);
    __builtin_memcpy(&b, &fb, 8);
    __hip_atomic_store((u64*)p,       a, __ATOMIC_RELAXED, __HIP_MEMORY_SCOPE_AGENT);
    __hip_atomic_store((u64*)(p + 2), b, __ATOMIC_RELAXED, __HIP_MEMORY_SCOPE_AGENT);
}

// ---- radix-4 Stockham stage (verified round-3/4 math), caller guards tid<128 ----
template<int P, int SH, bool INV>
__device__ __forceinline__ void r4b(const float* __restrict__ sR, const float* __restrict__ sI,
                                    float* __restrict__ dR, float* __restrict__ dI,
                                    const float* twr, const float* twi, int j) {
    int k  = j & (P - 1);
    int d0 = ((j - k) << 2) + k;
    float x0r = sR[j],       x0i = sI[j];
    float x1r = sR[j + 128], x1i = sI[j + 128];
    float x2r = sR[j + 256], x2i = sI[j + 256];
    float x3r = sR[j + 384], x3i = sI[j + 384];
    int tb = k << SH;
    float c1 = twr[tb], s1 = twi[tb];
    if (INV) s1 = -s1;
    float c2 = c1 * c1 - s1 * s1, s2 = 2.f * c1 * s1;
    float c3 = c1 * c2 - s1 * s2, s3 = c1 * s2 + s1 * c2;
    float a1r = x1r * c1 - x1i * s1, a1i = x1r * s1 + x1i * c1;
    float a2r = x2r * c2 - x2i * s2, a2i = x2r * s2 + x2i * c2;
    float a3r = x3r * c3 - x3i * s3, a3i = x3r * s3 + x3i * c3;
    float t0r = x0r + a2r, t0i = x0i + a2i;
    float t1r = x0r - a2r, t1i = x0i - a2i;
    float t2r = a1r + a3r, t2i = a1i + a3i;
    float t3r = a1r - a3r, t3i = a1i - a3i;
    float i3r = INV ? -t3i : t3i;
    float i3i = INV ?  t3r : -t3r;
    dR[d0]         = t0r + t2r;  dI[d0]         = t0i + t2i;
    dR[d0 + P]     = t1r + i3r;  dI[d0 + P]     = t1i + i3i;
    dR[d0 + 2 * P] = t0r - t2r;  dI[d0 + 2 * P] = t0i - t2i;
    dR[d0 + 3 * P] = t1r - i3r;  dI[d0 + 3 * P] = t1i - i3i;
}

// ================= k_init (round-3 verified, + barrier slot zeroing) =========
struct __align__(16) SMemI {
    float xb[NFFT];
    float C0r[NH], C0i[NH];
    float C1r[NH], C1i[NH];
    float win[NFFT];
    float twr[256], twi[256];
    float mag[516];
};

extern "C" __global__ __launch_bounds__(NT)
void k_init(const float* __restrict__ mel,
            const float* __restrict__ invmel,
            float* __restrict__ ws) {
    __shared__ SMemI sm;
    const int tid = threadIdx.x;
    const int t   = blockIdx.x;

    for (int n = tid; n < NFFT; n += NT) {
        double a = (2.0 * 3.14159265358979323846) * (double)n / 1024.0;
        sm.win[n] = (float)(0.5 - 0.5 * cos(a));
    }
    for (int j = tid; j < 256; j += NT) {
        double a = (2.0 * 3.14159265358979323846) * (double)j / 512.0;
        sm.twr[j] = (float)cos(a);
        sm.twi[j] = (float)(-sin(a));
    }
    __syncthreads();
    if (t == 0) {
        for (int n = tid; n < NFFT; n += NT) ws[TBL_WIN + n] = sm.win[n];
        for (int j = tid; j < 256; j += NT) {
            ws[TBL_TWR + j] = sm.twr[j];
            ws[TBL_TWI + j] = sm.twi[j];
        }
        for (int k = tid; k < NBINS; k += NT) {
            double a = (2.0 * 3.14159265358979323846) * (double)k / 1024.0;
            ws[TBL_W1R + k] = (float)cos(a);
            ws[TBL_W1I + k] = (float)sin(a);
        }
        // zero barrier state: 512 slots + gen
        ((int*)ws)[BAR_SLOT + tid]       = 0;
        ((int*)ws)[BAR_SLOT + 256 + tid] = 0;
        if (tid == 0) ((int*)ws)[BAR_GEN] = 0;
    }

    for (int p = t * NT + tid; p < SIGLEN; p += NFR * NT) {
        int tq = p >> 6, io = p & 63;
        float s = 0.f;
#pragma unroll
        for (int m = 0; m < 16; ++m) {
            int tp = tq - m;
            if (tp >= 0 && tp < NFR) {
                float w = sm.win[io + (m << 6)];
                s += w * w;
            }
        }
        ws[OFF_IWS + p] = (s > 1e-11f) ? (1.0f / s) : 1.0f;
    }

    if (tid < NMELS) sm.xb[tid] = exp10f(mel[tid * NFR + t]);
    __syncthreads();
    for (int k = tid; k < NBINS; k += NT) {
        const float* row = invmel + k * NMELS;
        float s = 0.f;
#pragma unroll 8
        for (int j = 0; j < NMELS; ++j) s += row[j] * sm.xb[j];
        ws[OFF_MAG + t * NBINS + k] = s;
        sm.mag[k] = s;
    }
    __syncthreads();

    // A[k] from real X = mag
    for (int k = tid; k < NH; k += NT) {
        float xr = sm.mag[k], yr = sm.mag[512 - k];
        double a = (2.0 * 3.14159265358979323846) * (double)k / 1024.0;
        float c = (float)cos(a), s = (float)sin(a);
        float dr = xr - yr;
        sm.C1r[k] = ((xr + yr) - s * dr) * (1.0f / 1024.0f);
        sm.C1i[k] = (c * dr) * (1.0f / 1024.0f);
    }
    // inverse FFT C1 -> C0
    __syncthreads();
    if (tid < 128) {
        float x0r = sm.C1r[tid],       x0i = sm.C1i[tid];
        float x1r = sm.C1r[tid + 128], x1i = sm.C1i[tid + 128];
        float x2r = sm.C1r[tid + 256], x2i = sm.C1i[tid + 256];
        float x3r = sm.C1r[tid + 384], x3i = sm.C1i[tid + 384];
        float t0r = x0r + x2r, t0i = x0i + x2i;
        float t1r = x0r - x2r, t1i = x0i - x2i;
        float t2r = x1r + x3r, t2i = x1i + x3i;
        float t3r = x1r - x3r, t3i = x1i - x3i;
        float4 vr = make_float4(t0r + t2r, t1r - t3i, t0r - t2r, t1r + t3i);
        float4 vi = make_float4(t0i + t2i, t1i + t3r, t0i - t2i, t1i - t3r);
        ((float4*)sm.C0r)[tid] = vr;
        ((float4*)sm.C0i)[tid] = vi;
    }
    __syncthreads();
    if (tid < 128) r4b<4, 5, true>(sm.C0r, sm.C0i, sm.C1r, sm.C1i, sm.twr, sm.twi, tid);
    __syncthreads();
    if (tid < 128) r4b<16, 3, true>(sm.C1r, sm.C1i, sm.C0r, sm.C0i, sm.twr, sm.twi, tid);
    __syncthreads();
    if (tid < 128) r4b<64, 1, true>(sm.C0r, sm.C0i, sm.C1r, sm.C1i, sm.twr, sm.twi, tid);
    __syncthreads();
    {
        float c = sm.twr[tid], s = -sm.twi[tid];
        float x0r = sm.C1r[tid], x0i = sm.C1i[tid];
        float x1r = sm.C1r[tid + 256], x1i = sm.C1i[tid + 256];
        float ar = x1r * c - x1i * s, ai = x1r * s + x1i * c;
        sm.C0r[tid]       = x0r + ar;  sm.C0i[tid]       = x0i + ai;
        sm.C0r[tid + 256] = x0r - ar;  sm.C0i[tid + 256] = x0i - ai;
    }
    __syncthreads();

    float4 w4 = ((float4*)sm.win)[tid];
    float4 o;
    o.x = w4.x * sm.C0r[2 * tid];
    o.y = w4.y * sm.C0i[2 * tid];
    o.z = w4.z * sm.C0r[2 * tid + 1];
    o.w = w4.w * sm.C0i[2 * tid + 1];
    *(float4*)&ws[OFF_F0 + (t << 10) + (tid << 2)] = o;
}

// ============== persistent Griffin-Lim: 1 frame/block, no cache fences =======
struct __align__(16) SM1 {
    float C0r[NH], C0i[NH];
    float C1r[NH], C1i[NH];
    float twr[256], twi[256];
};

extern "C" __global__ __launch_bounds__(NT)
void k_persist(float* __restrict__ ws, float* __restrict__ out) {
    __shared__ SM1 sm;
    const int tid = threadIdx.x;
    const int t   = blockIdx.x;       // frame owned
    const int i0  = tid << 2;
    const int j2  = 512 - tid;
    const int n0  = tid << 1;

    const float* tbl  = ws;
    const float* magg = ws + OFF_MAG;
    const float* iws  = ws + OFF_IWS;
    float* F0 = ws + OFF_F0;
    float* F1 = ws + OFF_F1;
    int*   bar = (int*)ws;

    // ---- one-time staging (normal cached loads; read-only, stays warm) ----
    if (tid < 64)       ((float4*)sm.twr)[tid]      = ((const float4*)(tbl + TBL_TWR))[tid];
    else if (tid < 128) ((float4*)sm.twi)[tid - 64] = ((const float4*)(tbl + TBL_TWI))[tid - 64];

    float4 w4 = ((const float4*)(tbl + TBL_WIN))[tid];
    float4 iw = *(const float4*)&iws[(t << 6) + i0];
    float m_a, m_b, m_ny = 0.f, w1r_a, w1i_a, w1r_b, w1i_b;
    {
        const int s0 = t * NBINS;
        if (tid == 0) {
            m_a = magg[s0]; m_ny = magg[s0 + 512]; m_b = magg[s0 + 256];
            w1r_a = 1.f; w1i_a = 0.f; w1r_b = 0.f; w1i_b = 1.f;
        } else {
            m_a = magg[s0 + tid]; m_b = magg[s0 + j2];
            w1r_a = tbl[TBL_W1R + tid]; w1i_a = tbl[TBL_W1I + tid];
            w1r_b = tbl[TBL_W1R + j2];  w1i_b = tbl[TBL_W1I + j2];
        }
    }
    const int io = i0 & 63;
    const int tq = t + (i0 >> 6);

#pragma unroll 1
    for (int it = 0; it < NITER; ++it) {
        const float* Fin  = (it & 1) ? F1 : F0;
        float*       Fout = (it & 1) ? F0 : F1;

        // ---- OLA gather via coherent L3 loads -> windowed packed z in C1 ----
        {
            float4 acc = make_float4(0.f, 0.f, 0.f, 0.f);
#pragma unroll
            for (int m = 0; m < 16; ++m) {
                int tp = tq - m;
                if (tp >= 0 && tp < NFR) {
                    float4 v = coh_load4(&Fin[(tp << 10) + io + (m << 6)]);
                    acc.x += v.x; acc.y += v.y; acc.z += v.z; acc.w += v.w;
                }
            }
            sm.C1r[n0]     = acc.x * iw.x * w4.x;
            sm.C1i[n0]     = acc.y * iw.y * w4.y;
            sm.C1r[n0 + 1] = acc.z * iw.z * w4.z;
            sm.C1i[n0 + 1] = acc.w * iw.w * w4.w;
        }

        // ---- forward FFT: C1 (packed z) -> C0 = Z ----
        __syncthreads();
        if (tid < 128) {
            float x0r = sm.C1r[tid],       x0i = sm.C1i[tid];
            float x1r = sm.C1r[tid + 128], x1i = sm.C1i[tid + 128];
            float x2r = sm.C1r[tid + 256], x2i = sm.C1i[tid + 256];
            float x3r = sm.C1r[tid + 384], x3i = sm.C1i[tid + 384];
            float t0r = x0r + x2r, t0i = x0i + x2i;
            float t1r = x0r - x2r, t1i = x0i - x2i;
            float t2r = x1r + x3r, t2i = x1i + x3i;
            float t3r = x1r - x3r, t3i = x1i - x3i;
            float4 vr = make_float4(t0r + t2r, t1r + t3i, t0r - t2r, t1r - t3i);
            float4 vi = make_float4(t0i + t2i, t1i - t3r, t0i - t2i, t1i + t3r);
            ((float4*)sm.C0r)[tid] = vr;
            ((float4*)sm.C0i)[tid] = vi;
        }
        __syncthreads();
        if (tid < 128) r4b<4, 5, false>(sm.C0r, sm.C0i, sm.C1r, sm.C1i, sm.twr, sm.twi, tid);
        __syncthreads();
        if (tid < 128) r4b<16, 3, false>(sm.C1r, sm.C1i, sm.C0r, sm.C0i, sm.twr, sm.twi, tid);
        __syncthreads();
        if (tid < 128) r4b<64, 1, false>(sm.C0r, sm.C0i, sm.C1r, sm.C1i, sm.twr, sm.twi, tid);
        __syncthreads();
        {
            float c = sm.twr[tid], s = sm.twi[tid];
            float x0r = sm.C1r[tid], x0i = sm.C1i[tid];
            float x1r = sm.C1r[tid + 256], x1i = sm.C1i[tid + 256];
            float ar = x1r * c - x1i * s, ai = x1r * s + x1i * c;
            sm.C0r[tid]       = x0r + ar;  sm.C0i[tid]       = x0i + ai;
            sm.C0r[tid + 256] = x0r - ar;  sm.C0i[tid + 256] = x0i - ai;
        }
        __syncthreads();

        // ---- fused unpack + phase projection + iFFT prep: C0 -> C1 ----
        if (tid == 0) {
            float zr = sm.C0r[0], zi = sm.C0i[0];
            float e0 = zr + zi;
            float e5 = zr - zi;
            float X0 = m_a  * e0 / fmaxf(1e-8f, fabsf(e0));
            float X5 = m_ny * e5 / fmaxf(1e-8f, fabsf(e5));
            sm.C1r[0] = (X0 + X5) * (1.0f / 1024.0f);
            sm.C1i[0] = (X0 - X5) * (1.0f / 1024.0f);
            float z6r = sm.C0r[256], z6i = sm.C0i[256];
            float sc6 = m_b / fmaxf(1e-8f, sqrtf(z6r * z6r + z6i * z6i));
            float X6r = z6r * sc6, X6i = -z6i * sc6;
            sm.C1r[256] = X6r * (2.0f / 1024.0f);
            sm.C1i[256] = -X6i * (2.0f / 1024.0f);
        } else {
            float zr = sm.C0r[tid], zi = sm.C0i[tid];
            float ur = sm.C0r[j2],  ui = sm.C0i[j2];
            float er = 0.5f * (zr + ur), ei = 0.5f * (zi - ui);
            float dr = zr - ur,          di = zi + ui;
            float odr = 0.5f * di, odi = -0.5f * dr;
            float e1r = er + w1r_a * odr + w1i_a * odi;
            float e1i = ei + w1r_a * odi - w1i_a * odr;
            float e2r =  er + w1r_b * odr - w1i_b * odi;
            float e2i = -ei - w1r_b * odi - w1i_b * odr;
            float sc1 = m_a / fmaxf(1e-8f, sqrtf(e1r * e1r + e1i * e1i));
            float sc2 = m_b / fmaxf(1e-8f, sqrtf(e2r * e2r + e2i * e2i));
            float X1r = e1r * sc1, X1i = e1i * sc1;
            float X2r = e2r * sc2, X2i = e2i * sc2;
            float Er = X1r + X2r, Ei = X1i - X2i;
            float Dr = X1r - X2r, Di = X1i + X2i;
            float wdr = w1r_a * Dr - w1i_a * Di, wdi = w1r_a * Di + w1i_a * Dr;
            sm.C1r[tid] = (Er - wdi) * (1.0f / 1024.0f);
            sm.C1i[tid] = (Ei + wdr) * (1.0f / 1024.0f);
            float wdr2 = -w1r_b * Dr - w1i_b * Di, wdi2 = w1r_b * Di - w1i_b * Dr;
            sm.C1r[j2] = (Er - wdi2) * (1.0f / 1024.0f);
            sm.C1i[j2] = (-Ei + wdr2) * (1.0f / 1024.0f);
        }
        __syncthreads();

        // ---- inverse FFT: C1 = A -> C0 = frame ----
        if (tid < 128) {
            float x0r = sm.C1r[tid],       x0i = sm.C1i[tid];
            float x1r = sm.C1r[tid + 128], x1i = sm.C1i[tid + 128];
            float x2r = sm.C1r[tid + 256], x2i = sm.C1i[tid + 256];
            float x3r = sm.C1r[tid + 384], x3i = sm.C1i[tid + 384];
            float t0r = x0r + x2r, t0i = x0i + x2i;
            float t1r = x0r - x2r, t1i = x0i - x2i;
            float t2r = x1r + x3r, t2i = x1i + x3i;
            float t3r = x1r - x3r, t3i = x1i - x3i;
            float4 vr = make_float4(t0r + t2r, t1r - t3i, t0r - t2r, t1r + t3i);
            float4 vi = make_float4(t0i + t2i, t1i + t3r, t0i - t2i, t1i - t3r);
            ((float4*)sm.C0r)[tid] = vr;
            ((float4*)sm.C0i)[tid] = vi;
        }
        __syncthreads();
        if (tid < 128) r4b<4, 5, true>(sm.C0r, sm.C0i, sm.C1r, sm.C1i, sm.twr, sm.twi, tid);
        __syncthreads();
        if (tid < 128) r4b<16, 3, true>(sm.C1r, sm.C1i, sm.C0r, sm.C0i, sm.twr, sm.twi, tid);
        __syncthreads();
        if (tid < 128) r4b<64, 1, true>(sm.C0r, sm.C0i, sm.C1r, sm.C1i, sm.twr, sm.twi, tid);
        __syncthreads();
        {
            float c = sm.twr[tid], s = -sm.twi[tid];
            float x0r = sm.C1r[tid], x0i = sm.C1i[tid];
            float x1r = sm.C1r[tid + 256], x1i = sm.C1i[tid + 256];
            float ar = x1r * c - x1i * s, ai = x1r * s + x1i * c;
            sm.C0r[tid]       = x0r + ar;  sm.C0i[tid]       = x0i + ai;
            sm.C0r[tid + 256] = x0r - ar;  sm.C0i[tid + 256] = x0i - ai;
        }
        __syncthreads();

        // ---- store windowed frame (write-through, coherent at L3) ----
        {
            float4 o;
            o.x = w4.x * sm.C0r[n0];
            o.y = w4.y * sm.C0i[n0];
            o.z = w4.z * sm.C0r[n0 + 1];
            o.w = w4.w * sm.C0i[n0 + 1];
            coh_store4(&Fout[(t << 10) + i0], o);
        }

        // ---- grid barrier: slot array + generation word, no cache fences ----
        // __syncthreads drains vmcnt(0): frame stores are at L3 before slot store.
        __syncthreads();
        if (tid == 0)
            __hip_atomic_store(bar + BAR_SLOT + t, it + 1,
                               __ATOMIC_RELAXED, __HIP_MEMORY_SCOPE_AGENT);
        if (t == 0) {
            // block 0: each thread watches 2 slots, then releases the generation
            while (__hip_atomic_load(bar + BAR_SLOT + tid,
                                     __ATOMIC_RELAXED, __HIP_MEMORY_SCOPE_AGENT) <= it)
                __builtin_amdgcn_s_sleep(1);
            while (__hip_atomic_load(bar + BAR_SLOT + 256 + tid,
                                     __ATOMIC_RELAXED, __HIP_MEMORY_SCOPE_AGENT) <= it)
                __builtin_amdgcn_s_sleep(1);
            __syncthreads();
            if (tid == 0)
                __hip_atomic_store(bar + BAR_GEN, it + 1,
                                   __ATOMIC_RELAXED, __HIP_MEMORY_SCOPE_AGENT);
        }
        if (tid == 0) {
            while (__hip_atomic_load(bar + BAR_GEN,
                                     __ATOMIC_RELAXED, __HIP_MEMORY_SCOPE_AGENT) <= it)
                __builtin_amdgcn_s_sleep(2);
        }
        __syncthreads();
    }

    // ---- epilogue: final OLA (F0) -> out (coherent loads, normal out store) ----
    int p0 = (t * NT + tid) << 2;
    if (p0 < SIGLEN) {
        int tqq = p0 >> 6, ioo = p0 & 63;
        float4 acc = make_float4(0.f, 0.f, 0.f, 0.f);
#pragma unroll
        for (int m = 0; m < 16; ++m) {
            int tp = tqq - m;
            if (tp >= 0 && tp < NFR) {
                float4 v = coh_load4(&F0[(tp << 10) + ioo + (m << 6)]);
                acc.x += v.x; acc.y += v.y; acc.z += v.z; acc.w += v.w;
            }
        }
        float4 iwf = *(const float4*)&iws[p0];
        float4 o = make_float4(acc.x * iwf.x, acc.y * iwf.y, acc.z * iwf.z, acc.w * iwf.w);
        *(float4*)&out[p0] = o;
    }
}

extern "C" void kernel_launch(void* const* d_in, const int* in_sizes, int n_in,
                              void* d_out, int out_size, void* d_ws, size_t ws_size,
                              hipStream_t stream) {
    const float* mel    = (const float*)d_in[0];
    const float* invmel = (const float*)d_in[1];
    float* out = (float*)d_out;
    float* ws  = (float*)d_ws;

    k_init<<<NFR, NT, 0, stream>>>(mel, invmel, ws);
    k_persist<<<NB, NT, 0, stream>>>(ws, out);
}

// Round 7
// 3107.543 us; speedup vs baseline: 4.6454x; 1.1079x over previous
//
#include <hip/hip_runtime.h>
#include <math.h>

#define NFFT   1024
#define NH     512
#define HOP    64
#define NMELS  80
#define NFR    512
#define NBINS  513
#define NITER  300
#define SIGLEN 33728
#define NSEG   527
#define NT     256
#define NB     512

// ---- workspace layout (4B units) ----
#define TBL_WIN  0          // win[1024]
#define TBL_TWR  1024       // twr[256]
#define TBL_TWI  1280       // twi[256]
#define TBL_W1R  1536       // w1r[513]
#define TBL_W1I  2056       // w1i[513]
#define BAR_SLOT 2624       // 512 int slots
#define BAR_GEN  3200       // generation word
#define OFF_MAG  4096       // mag[512*513]
#define OFF_IWS  266752     // iws[33728]
#define OFF_F    300480     // F[512*1024]
#define OFF_X    824768     // x[33792]

typedef unsigned long long u64;
typedef unsigned int u32;

// ---- coherent (agent-scope sc1, L3-point) accessors ----
__device__ __forceinline__ float4 coh_load4(const float* p) {
    u64 a = __hip_atomic_load((const u64*)p,       __ATOMIC_RELAXED, __HIP_MEMORY_SCOPE_AGENT);
    u64 b = __hip_atomic_load((const u64*)(p + 2), __ATOMIC_RELAXED, __HIP_MEMORY_SCOPE_AGENT);
    float2 fa, fb;
    __builtin_memcpy(&fa, &a, 8);
    __builtin_memcpy(&fb, &b, 8);
    return make_float4(fa.x, fa.y, fb.x, fb.y);
}
__device__ __forceinline__ void coh_store4(float* p, float4 v) {
    float2 fa = make_float2(v.x, v.y), fb = make_float2(v.z, v.w);
    u64 a, b;
    __builtin_memcpy(&a, &fa, 8);
    __builtin_memcpy(&b, &fb, 8);
    __hip_atomic_store((u64*)p,       a, __ATOMIC_RELAXED, __HIP_MEMORY_SCOPE_AGENT);
    __hip_atomic_store((u64*)(p + 2), b, __ATOMIC_RELAXED, __HIP_MEMORY_SCOPE_AGENT);
}
__device__ __forceinline__ float coh_load1(const float* p) {
    u32 a = __hip_atomic_load((const u32*)p, __ATOMIC_RELAXED, __HIP_MEMORY_SCOPE_AGENT);
    float f;
    __builtin_memcpy(&f, &a, 4);
    return f;
}
__device__ __forceinline__ void coh_store1(float* p, float v) {
    u32 a;
    __builtin_memcpy(&a, &v, 4);
    __hip_atomic_store((u32*)p, a, __ATOMIC_RELAXED, __HIP_MEMORY_SCOPE_AGENT);
}

// ---- radix-4 Stockham stage (verified), caller guards tid<128 ----
template<int P, int SH, bool INV>
__device__ __forceinline__ void r4b(const float* __restrict__ sR, const float* __restrict__ sI,
                                    float* __restrict__ dR, float* __restrict__ dI,
                                    const float* twr, const float* twi, int j) {
    int k  = j & (P - 1);
    int d0 = ((j - k) << 2) + k;
    float x0r = sR[j],       x0i = sI[j];
    float x1r = sR[j + 128], x1i = sI[j + 128];
    float x2r = sR[j + 256], x2i = sI[j + 256];
    float x3r = sR[j + 384], x3i = sI[j + 384];
    int tb = k << SH;
    float c1 = twr[tb], s1 = twi[tb];
    if (INV) s1 = -s1;
    float c2 = c1 * c1 - s1 * s1, s2 = 2.f * c1 * s1;
    float c3 = c1 * c2 - s1 * s2, s3 = c1 * s2 + s1 * c2;
    float a1r = x1r * c1 - x1i * s1, a1i = x1r * s1 + x1i * c1;
    float a2r = x2r * c2 - x2i * s2, a2i = x2r * s2 + x2i * c2;
    float a3r = x3r * c3 - x3i * s3, a3i = x3r * s3 + x3i * c3;
    float t0r = x0r + a2r, t0i = x0i + a2i;
    float t1r = x0r - a2r, t1i = x0i - a2i;
    float t2r = a1r + a3r, t2i = a1i + a3i;
    float t3r = a1r - a3r, t3i = a1i - a3i;
    float i3r = INV ? -t3i : t3i;
    float i3i = INV ?  t3r : -t3r;
    dR[d0]         = t0r + t2r;  dI[d0]         = t0i + t2i;
    dR[d0 + P]     = t1r + i3r;  dI[d0 + P]     = t1i + i3i;
    dR[d0 + 2 * P] = t0r - t2r;  dI[d0 + 2 * P] = t0i - t2i;
    dR[d0 + 3 * P] = t1r - i3r;  dI[d0 + 3 * P] = t1i - i3i;
}

// ================= k_init (round-3/5 verified) ===============================
struct __align__(16) SMemI {
    float xb[NFFT];
    float C0r[NH], C0i[NH];
    float C1r[NH], C1i[NH];
    float win[NFFT];
    float twr[256], twi[256];
    float mag[516];
};

extern "C" __global__ __launch_bounds__(NT)
void k_init(const float* __restrict__ mel,
            const float* __restrict__ invmel,
            float* __restrict__ ws) {
    __shared__ SMemI sm;
    const int tid = threadIdx.x;
    const int t   = blockIdx.x;

    for (int n = tid; n < NFFT; n += NT) {
        double a = (2.0 * 3.14159265358979323846) * (double)n / 1024.0;
        sm.win[n] = (float)(0.5 - 0.5 * cos(a));
    }
    for (int j = tid; j < 256; j += NT) {
        double a = (2.0 * 3.14159265358979323846) * (double)j / 512.0;
        sm.twr[j] = (float)cos(a);
        sm.twi[j] = (float)(-sin(a));
    }
    __syncthreads();
    if (t == 0) {
        for (int n = tid; n < NFFT; n += NT) ws[TBL_WIN + n] = sm.win[n];
        for (int j = tid; j < 256; j += NT) {
            ws[TBL_TWR + j] = sm.twr[j];
            ws[TBL_TWI + j] = sm.twi[j];
        }
        for (int k = tid; k < NBINS; k += NT) {
            double a = (2.0 * 3.14159265358979323846) * (double)k / 1024.0;
            ws[TBL_W1R + k] = (float)cos(a);
            ws[TBL_W1I + k] = (float)sin(a);
        }
        // zero barrier state: 512 slots + gen
        ((int*)ws)[BAR_SLOT + tid]       = 0;
        ((int*)ws)[BAR_SLOT + 256 + tid] = 0;
        if (tid == 0) ((int*)ws)[BAR_GEN] = 0;
    }

    for (int p = t * NT + tid; p < SIGLEN; p += NFR * NT) {
        int tq = p >> 6, io = p & 63;
        float s = 0.f;
#pragma unroll
        for (int m = 0; m < 16; ++m) {
            int tp = tq - m;
            if (tp >= 0 && tp < NFR) {
                float w = sm.win[io + (m << 6)];
                s += w * w;
            }
        }
        ws[OFF_IWS + p] = (s > 1e-11f) ? (1.0f / s) : 1.0f;
    }

    if (tid < NMELS) sm.xb[tid] = exp10f(mel[tid * NFR + t]);
    __syncthreads();
    for (int k = tid; k < NBINS; k += NT) {
        const float* row = invmel + k * NMELS;
        float s = 0.f;
#pragma unroll 8
        for (int j = 0; j < NMELS; ++j) s += row[j] * sm.xb[j];
        ws[OFF_MAG + t * NBINS + k] = s;
        sm.mag[k] = s;
    }
    __syncthreads();

    // A[k] from real X = mag
    for (int k = tid; k < NH; k += NT) {
        float xr = sm.mag[k], yr = sm.mag[512 - k];
        double a = (2.0 * 3.14159265358979323846) * (double)k / 1024.0;
        float c = (float)cos(a), s = (float)sin(a);
        float dr = xr - yr;
        sm.C1r[k] = ((xr + yr) - s * dr) * (1.0f / 1024.0f);
        sm.C1i[k] = (c * dr) * (1.0f / 1024.0f);
    }
    // inverse FFT C1 -> C0
    __syncthreads();
    if (tid < 128) {
        float x0r = sm.C1r[tid],       x0i = sm.C1i[tid];
        float x1r = sm.C1r[tid + 128], x1i = sm.C1i[tid + 128];
        float x2r = sm.C1r[tid + 256], x2i = sm.C1i[tid + 256];
        float x3r = sm.C1r[tid + 384], x3i = sm.C1i[tid + 384];
        float t0r = x0r + x2r, t0i = x0i + x2i;
        float t1r = x0r - x2r, t1i = x0i - x2i;
        float t2r = x1r + x3r, t2i = x1i + x3i;
        float t3r = x1r - x3r, t3i = x1i - x3i;
        float4 vr = make_float4(t0r + t2r, t1r - t3i, t0r - t2r, t1r + t3i);
        float4 vi = make_float4(t0i + t2i, t1i + t3r, t0i - t2i, t1i - t3r);
        ((float4*)sm.C0r)[tid] = vr;
        ((float4*)sm.C0i)[tid] = vi;
    }
    __syncthreads();
    if (tid < 128) r4b<4, 5, true>(sm.C0r, sm.C0i, sm.C1r, sm.C1i, sm.twr, sm.twi, tid);
    __syncthreads();
    if (tid < 128) r4b<16, 3, true>(sm.C1r, sm.C1i, sm.C0r, sm.C0i, sm.twr, sm.twi, tid);
    __syncthreads();
    if (tid < 128) r4b<64, 1, true>(sm.C0r, sm.C0i, sm.C1r, sm.C1i, sm.twr, sm.twi, tid);
    __syncthreads();
    {
        float c = sm.twr[tid], s = -sm.twi[tid];
        float x0r = sm.C1r[tid], x0i = sm.C1i[tid];
        float x1r = sm.C1r[tid + 256], x1i = sm.C1i[tid + 256];
        float ar = x1r * c - x1i * s, ai = x1r * s + x1i * c;
        sm.C0r[tid]       = x0r + ar;  sm.C0i[tid]       = x0i + ai;
        sm.C0r[tid + 256] = x0r - ar;  sm.C0i[tid + 256] = x0i - ai;
    }
    __syncthreads();

    float4 w4 = ((float4*)sm.win)[tid];
    float4 o;
    o.x = w4.x * sm.C0r[2 * tid];
    o.y = w4.y * sm.C0i[2 * tid];
    o.z = w4.z * sm.C0r[2 * tid + 1];
    o.w = w4.w * sm.C0i[2 * tid + 1];
    *(float4*)&ws[OFF_F + (t << 10) + (tid << 2)] = o;
}

// ============== persistent Griffin-Lim: global barrier, X materialized ======
struct __align__(16) SM1 {
    float C0r[NH], C0i[NH];
    float C1r[NH], C1i[NH];
    float twr[256], twi[256];
};

// round-5-proven global barrier: slot array + generation word, relaxed sc1.
// __syncthreads at entry drains vmcnt -> prior sc1 stores are at L3.
__device__ __forceinline__ void gbar(int* bar, int t, int tid, int bc) {
    __syncthreads();
    if (tid == 0)
        __hip_atomic_store(bar + BAR_SLOT + t, bc,
                           __ATOMIC_RELAXED, __HIP_MEMORY_SCOPE_AGENT);
    if (t == 0) {
        while (__hip_atomic_load(bar + BAR_SLOT + tid,
                                 __ATOMIC_RELAXED, __HIP_MEMORY_SCOPE_AGENT) < bc)
            __builtin_amdgcn_s_sleep(1);
        while (__hip_atomic_load(bar + BAR_SLOT + 256 + tid,
                                 __ATOMIC_RELAXED, __HIP_MEMORY_SCOPE_AGENT) < bc)
            __builtin_amdgcn_s_sleep(1);
        __syncthreads();
        if (tid == 0)
            __hip_atomic_store(bar + BAR_GEN, bc,
                               __ATOMIC_RELAXED, __HIP_MEMORY_SCOPE_AGENT);
    }
    if (tid == 0) {
        while (__hip_atomic_load(bar + BAR_GEN,
                                 __ATOMIC_RELAXED, __HIP_MEMORY_SCOPE_AGENT) < bc)
            __builtin_amdgcn_s_sleep(2);
    }
    __syncthreads();
}

extern "C" __global__ __launch_bounds__(NT)
void k_persist(float* __restrict__ ws, float* __restrict__ out) {
    __shared__ SM1 sm;
    const int tid = threadIdx.x;
    const int t   = blockIdx.x;       // frame owned
    const int i0  = tid << 2;
    const int j2  = 512 - tid;
    const int n0  = tid << 1;

    const float* tbl  = ws;
    const float* magg = ws + OFF_MAG;
    const float* iws  = ws + OFF_IWS;
    float* F  = ws + OFF_F;
    float* X  = ws + OFF_X;
    int*   bar = (int*)ws;

    // ---- one-time staging ----
    if (tid < 64)       ((float4*)sm.twr)[tid]      = ((const float4*)(tbl + TBL_TWR))[tid];
    else if (tid < 128) ((float4*)sm.twi)[tid - 64] = ((const float4*)(tbl + TBL_TWI))[tid - 64];

    float4 w4 = ((const float4*)(tbl + TBL_WIN))[tid];
    float m_a, m_b, m_ny = 0.f, w1r_a, w1i_a, w1r_b, w1i_b;
    {
        const int s0 = t * NBINS;
        if (tid == 0) {
            m_a = magg[s0]; m_ny = magg[s0 + 512]; m_b = magg[s0 + 256];
            w1r_a = 1.f; w1i_a = 0.f; w1r_b = 0.f; w1i_b = 1.f;
        } else {
            m_a = magg[s0 + tid]; m_b = magg[s0 + j2];
            w1r_a = tbl[TBL_W1R + tid]; w1i_a = tbl[TBL_W1I + tid];
            w1r_b = tbl[TBL_W1R + j2];  w1i_b = tbl[TBL_W1I + j2];
        }
    }
    // segment ownership: seg t (lanes 0..63); blocks >=497 also seg t+15 (lanes 64..127)
    const bool extra = (t >= 497);
    int gseg = -1;
    if (tid < 64) gseg = t;
    else if (tid < 128 && extra) gseg = t + 15;
    const int u = tid & 63;
    float iwreg = 0.f;
    if (gseg >= 0) iwreg = iws[(gseg << 6) + u];

    // ---- prologue: x^0 segment(s) from k_init frames ----
    if (gseg >= 0) {
        float acc = 0.f;
#pragma unroll
        for (int m = 0; m < 16; ++m) {
            int tp = gseg - m;
            if (tp >= 0 && tp < NFR)
                acc += coh_load1(&F[(tp << 10) + u + (m << 6)]);
        }
        coh_store1(&X[(gseg << 6) + u], acc * iwreg);
    }
    gbar(bar, t, tid, 1);

    int bc = 2;
#pragma unroll 1
    for (int it = 1; it <= NITER; ++it) {
        // ===== phase A: stft + projection + istft, write frame F[t] =====
        {   // x window * win -> packed z in C1
            float4 xv = coh_load4(&X[(t << 6) + i0]);
            sm.C1r[n0]     = xv.x * w4.x;
            sm.C1i[n0]     = xv.y * w4.y;
            sm.C1r[n0 + 1] = xv.z * w4.z;
            sm.C1i[n0 + 1] = xv.w * w4.w;
        }
        __syncthreads();
        // forward FFT: C1 -> C0
        if (tid < 128) {
            float x0r = sm.C1r[tid],       x0i = sm.C1i[tid];
            float x1r = sm.C1r[tid + 128], x1i = sm.C1i[tid + 128];
            float x2r = sm.C1r[tid + 256], x2i = sm.C1i[tid + 256];
            float x3r = sm.C1r[tid + 384], x3i = sm.C1i[tid + 384];
            float t0r = x0r + x2r, t0i = x0i + x2i;
            float t1r = x0r - x2r, t1i = x0i - x2i;
            float t2r = x1r + x3r, t2i = x1i + x3i;
            float t3r = x1r - x3r, t3i = x1i - x3i;
            float4 vr = make_float4(t0r + t2r, t1r + t3i, t0r - t2r, t1r - t3i);
            float4 vi = make_float4(t0i + t2i, t1i - t3r, t0i - t2i, t1i + t3r);
            ((float4*)sm.C0r)[tid] = vr;
            ((float4*)sm.C0i)[tid] = vi;
        }
        __syncthreads();
        if (tid < 128) r4b<4, 5, false>(sm.C0r, sm.C0i, sm.C1r, sm.C1i, sm.twr, sm.twi, tid);
        __syncthreads();
        if (tid < 128) r4b<16, 3, false>(sm.C1r, sm.C1i, sm.C0r, sm.C0i, sm.twr, sm.twi, tid);
        __syncthreads();
        if (tid < 128) r4b<64, 1, false>(sm.C0r, sm.C0i, sm.C1r, sm.C1i, sm.twr, sm.twi, tid);
        __syncthreads();
        {
            float c = sm.twr[tid], s = sm.twi[tid];
            float x0r = sm.C1r[tid], x0i = sm.C1i[tid];
            float x1r = sm.C1r[tid + 256], x1i = sm.C1i[tid + 256];
            float ar = x1r * c - x1i * s, ai = x1r * s + x1i * c;
            sm.C0r[tid]       = x0r + ar;  sm.C0i[tid]       = x0i + ai;
            sm.C0r[tid + 256] = x0r - ar;  sm.C0i[tid + 256] = x0i - ai;
        }
        __syncthreads();

        // fused unpack + phase projection + iFFT prep: C0 -> C1
        if (tid == 0) {
            float zr = sm.C0r[0], zi = sm.C0i[0];
            float e0 = zr + zi;
            float e5 = zr - zi;
            float X0 = m_a  * e0 / fmaxf(1e-8f, fabsf(e0));
            float X5 = m_ny * e5 / fmaxf(1e-8f, fabsf(e5));
            sm.C1r[0] = (X0 + X5) * (1.0f / 1024.0f);
            sm.C1i[0] = (X0 - X5) * (1.0f / 1024.0f);
            float z6r = sm.C0r[256], z6i = sm.C0i[256];
            float sc6 = m_b / fmaxf(1e-8f, sqrtf(z6r * z6r + z6i * z6i));
            float X6r = z6r * sc6, X6i = -z6i * sc6;
            sm.C1r[256] = X6r * (2.0f / 1024.0f);
            sm.C1i[256] = -X6i * (2.0f / 1024.0f);
        } else {
            float zr = sm.C0r[tid], zi = sm.C0i[tid];
            float ur = sm.C0r[j2],  ui = sm.C0i[j2];
            float er = 0.5f * (zr + ur), ei = 0.5f * (zi - ui);
            float dr = zr - ur,          di = zi + ui;
            float odr = 0.5f * di, odi = -0.5f * dr;
            float e1r = er + w1r_a * odr + w1i_a * odi;
            float e1i = ei + w1r_a * odi - w1i_a * odr;
            float e2r =  er + w1r_b * odr - w1i_b * odi;
            float e2i = -ei - w1r_b * odi - w1i_b * odr;
            float sc1 = m_a / fmaxf(1e-8f, sqrtf(e1r * e1r + e1i * e1i));
            float sc2 = m_b / fmaxf(1e-8f, sqrtf(e2r * e2r + e2i * e2i));
            float X1r = e1r * sc1, X1i = e1i * sc1;
            float X2r = e2r * sc2, X2i = e2i * sc2;
            float Er = X1r + X2r, Ei = X1i - X2i;
            float Dr = X1r - X2r, Di = X1i + X2i;
            float wdr = w1r_a * Dr - w1i_a * Di, wdi = w1r_a * Di + w1i_a * Dr;
            sm.C1r[tid] = (Er - wdi) * (1.0f / 1024.0f);
            sm.C1i[tid] = (Ei + wdr) * (1.0f / 1024.0f);
            float wdr2 = -w1r_b * Dr - w1i_b * Di, wdi2 = w1r_b * Di - w1i_b * Dr;
            sm.C1r[j2] = (Er - wdi2) * (1.0f / 1024.0f);
            sm.C1i[j2] = (-Ei + wdr2) * (1.0f / 1024.0f);
        }
        __syncthreads();

        // inverse FFT: C1 -> C0
        if (tid < 128) {
            float x0r = sm.C1r[tid],       x0i = sm.C1i[tid];
            float x1r = sm.C1r[tid + 128], x1i = sm.C1i[tid + 128];
            float x2r = sm.C1r[tid + 256], x2i = sm.C1i[tid + 256];
            float x3r = sm.C1r[tid + 384], x3i = sm.C1i[tid + 384];
            float t0r = x0r + x2r, t0i = x0i + x2i;
            float t1r = x0r - x2r, t1i = x0i - x2i;
            float t2r = x1r + x3r, t2i = x1i + x3i;
            float t3r = x1r - x3r, t3i = x1i - x3i;
            float4 vr = make_float4(t0r + t2r, t1r - t3i, t0r - t2r, t1r + t3i);
            float4 vi = make_float4(t0i + t2i, t1i + t3r, t0i - t2i, t1i - t3r);
            ((float4*)sm.C0r)[tid] = vr;
            ((float4*)sm.C0i)[tid] = vi;
        }
        __syncthreads();
        if (tid < 128) r4b<4, 5, true>(sm.C0r, sm.C0i, sm.C1r, sm.C1i, sm.twr, sm.twi, tid);
        __syncthreads();
        if (tid < 128) r4b<16, 3, true>(sm.C1r, sm.C1i, sm.C0r, sm.C0i, sm.twr, sm.twi, tid);
        __syncthreads();
        if (tid < 128) r4b<64, 1, true>(sm.C0r, sm.C0i, sm.C1r, sm.C1i, sm.twr, sm.twi, tid);
        __syncthreads();
        {
            float c = sm.twr[tid], s = -sm.twi[tid];
            float x0r = sm.C1r[tid], x0i = sm.C1i[tid];
            float x1r = sm.C1r[tid + 256], x1i = sm.C1i[tid + 256];
            float ar = x1r * c - x1i * s, ai = x1r * s + x1i * c;
            sm.C0r[tid]       = x0r + ar;  sm.C0i[tid]       = x0i + ai;
            sm.C0r[tid + 256] = x0r - ar;  sm.C0i[tid + 256] = x0i - ai;
        }
        __syncthreads();

        // store windowed frame (sc1, at L3)
        {
            float4 o;
            o.x = w4.x * sm.C0r[n0];
            o.y = w4.y * sm.C0i[n0];
            o.z = w4.z * sm.C0r[n0 + 1];
            o.w = w4.w * sm.C0i[n0 + 1];
            coh_store4(&F[(t << 10) + i0], o);
        }
        gbar(bar, t, tid, bc++);   // F^{it} complete everywhere

        // ===== phase B: OLA own segment(s) =====
        if (gseg >= 0) {
            float acc = 0.f;
#pragma unroll
            for (int m = 0; m < 16; ++m) {
                int tp = gseg - m;
                if (tp >= 0 && tp < NFR)
                    acc += coh_load1(&F[(tp << 10) + u + (m << 6)]);
            }
            float val = acc * iwreg;
            if (it < NITER) coh_store1(&X[(gseg << 6) + u], val);
            else            out[(gseg << 6) + u] = val;
        }
        if (it < NITER)
            gbar(bar, t, tid, bc++);   // x^{it} complete everywhere
    }
}

extern "C" void kernel_launch(void* const* d_in, const int* in_sizes, int n_in,
                              void* d_out, int out_size, void* d_ws, size_t ws_size,
                              hipStream_t stream) {
    const float* mel    = (const float*)d_in[0];
    const float* invmel = (const float*)d_in[1];
    float* out = (float*)d_out;
    float* ws  = (float*)d_ws;

    k_init<<<NFR, NT, 0, stream>>>(mel, invmel, ws);
    k_persist<<<NB, NT, 0, stream>>>(ws, out);
}